// Round 7
// baseline (683.198 us; speedup 1.0000x reference)
//
#include <hip/hip_runtime.h>
#include <hip/hip_bf16.h>

// DA-RNN persistent kernel, round 7 = round 6 structure at 2 blocks/CU.
// R6 showed 1 block/CU (LDS 137KB): every barrier/latency chain stalled the
// whole CU. R7: BB=2, 512 blocks x 512 threads (16 waves/CU) -> two
// independent blocks per CU overlap each other's barrier drains and
// shuffle/trans latency chains. LDS cut to ~76KB/block: halved row buffers,
// fc_w -> registers, alias regions (encb <-> decb+dwih, se <-> sd) rewritten
// at the encoder->decoder boundary. __launch_bounds__(512,4) caps VGPR at 128.

#define B_    1024
#define T_    64
#define D_    128
#define H_    128
#define HOR_  24
#define ATT_  64
#define BB    2
#define LOG2E 1.4426950408889634f
#define C127  (1.f/127.f)

typedef float f32x4  __attribute__((ext_vector_type(4)));
typedef short bf16x8 __attribute__((ext_vector_type(8)));
typedef int   i32x4  __attribute__((ext_vector_type(4)));

#define MFMA16(a,b,c) __builtin_amdgcn_mfma_f32_16x16x32_bf16((a),(b),(c),0,0,0)
#define MFMAI8(a,b,c) __builtin_amdgcn_mfma_i32_16x16x64_i8((a),(b),(c),0,0,0)

// ---- workspace layout (same packing as R5/R6) ----
#define WHS_E    0        // base GEMM  B bf16: kt0..7, nt0..3  (16384 el)
#define WDDC_E   16384    // dc GEMM    B bf16: kt0..7, nt0..3  (16384 el)
#define WDENC_E  32768    // proj GEMM  B bf16: kt0..3, nt0..3  ( 8192 el)
#define WENC8_B  81920    // i8 enc gates B: [kt4][nt32][lane64][16] (131072 B)
#define WDEC8_B  212992   // i8 dec gates B: [kt2][nt32][lane64][16] ( 65536 B)
#define SENC_B   278528   // 512 f32 per-col scales (enc)
#define SDEC_B   280576   // 512 f32 per-col scales (dec)

__device__ __forceinline__ short f2b(float f) {        // fp32 -> bf16 RNE
  union { float f; unsigned u; } c; c.f = f;
  unsigned r = c.u + 0x7fffu + ((c.u >> 16) & 1u);
  return (short)(r >> 16);
}
__device__ __forceinline__ float b2f(short s) {
  union { unsigned u; float f; } c; c.u = ((unsigned)(unsigned short)s) << 16;
  return c.f;
}
__device__ __forceinline__ float fexp2(float x) { return __builtin_amdgcn_exp2f(x); }
__device__ __forceinline__ float frcp (float x) { return __builtin_amdgcn_rcpf(x); }
__device__ __forceinline__ float tanh_acc(float x) {   // 1 - 2/(1+e^{2x})
  float e = fexp2(x * 2.885390081777927f);
  return 1.f - 2.f * frcp(1.f + e);
}
__device__ __forceinline__ float sigm(float x) {
  return frcp(1.f + fexp2(-LOG2E * x));
}
__device__ __forceinline__ float wsum64(float v) {
#pragma unroll
  for (int o = 32; o > 0; o >>= 1) v += __shfl_xor(v, o, 64);
  return v;
}
__device__ __forceinline__ float wmax64(float v) {
#pragma unroll
  for (int o = 32; o > 0; o >>= 1) v = fmaxf(v, __shfl_xor(v, o, 64));
  return v;
}

// ---- prep1: bf16 B-frags (base / dc / proj), one element per thread ----
__global__ void prep_bf(const float* __restrict__ We_w,
                        const float* __restrict__ Wd_w,
                        char* __restrict__ ws8) {
  int e = blockIdx.x * 256 + threadIdx.x;
  if (e >= 40960) return;
  short* f16 = (short*)ws8;
  int region = e >> 14;                  // 0=WHS 1=WDDC 2=WDENC
  int er = e & 16383;
  int fi = er >> 9, li = (er >> 3) & 63, jq = er & 7;
  int kt = fi >> 2, nt = fi & 3;
  int k = kt * 32 + ((li >> 4) << 3) + jq, n = nt * 16 + (li & 15);
  float v;
  if (region == 0)      v = We_w[n * 257 + k];
  else if (region == 1) v = (k < 128) ? Wd_w[n * 384 + 128 + k]
                                      : Wd_w[n * 384 + 256 + (k - 128)];
  else                  v = Wd_w[n * 384 + k];
  f16[e] = f2b(v);
}

// ---- prep2: i8 quantized gates weights, one wave per column ----
__global__ void prep_q(const float* __restrict__ enc_Wih,
                       const float* __restrict__ enc_Whh,
                       const float* __restrict__ dec_Whh,
                       char* __restrict__ ws8) {
  int gw = (blockIdx.x * 256 + threadIdx.x) >> 6;
  int lane = threadIdx.x & 63;
  if (gw < 512) {                        // encoder col, K=256
    int n = gw;
    float v[4]; float m = 0.f;
#pragma unroll
    for (int q = 0; q < 4; ++q) {
      int k = lane * 4 + q;
      v[q] = (k < 128) ? enc_Wih[n * 128 + k] : enc_Whh[n * 128 + (k - 128)];
      m = fmaxf(m, fabsf(v[q]));
    }
    m = wmax64(m);
    if (lane == 0) ((float*)(ws8 + SENC_B))[n] = m * C127;
    float inv = m > 0.f ? 127.f / m : 0.f;
    char* dst = ws8 + WENC8_B;
#pragma unroll
    for (int q = 0; q < 4; ++q) {
      int k = lane * 4 + q;
      int kt = k >> 6, grp = (k >> 4) & 3, b = k & 15, l16 = (n & 15) | (grp << 4);
      dst[((kt * 32 + (n >> 4)) * 64 + l16) * 16 + b] = (char)(int)rintf(v[q] * inv);
    }
  } else if (gw < 1024) {                // decoder col, K=128
    int n = gw - 512;
    float v[2]; float m = 0.f;
#pragma unroll
    for (int q = 0; q < 2; ++q) {
      int k = lane * 2 + q;
      v[q] = dec_Whh[n * 128 + k];
      m = fmaxf(m, fabsf(v[q]));
    }
    m = wmax64(m);
    if (lane == 0) ((float*)(ws8 + SDEC_B))[n] = m * C127;
    float inv = m > 0.f ? 127.f / m : 0.f;
    char* dst = ws8 + WDEC8_B;
#pragma unroll
    for (int q = 0; q < 2; ++q) {
      int k = lane * 2 + q;
      int kt = k >> 6, grp = (k >> 4) & 3, b = k & 15, l16 = (n & 15) | (grp << 4);
      dst[((kt * 32 + (n >> 4)) * 64 + l16) * 16 + b] = (char)(int)rintf(v[q] * inv);
    }
  }
}

__global__ __launch_bounds__(512, 4)
void da_rnn(const float* __restrict__ X, const float* __restrict__ y_hist,
            const float* __restrict__ We_w, const float* __restrict__ We_b,
            const float* __restrict__ ve_w,
            const float* __restrict__ enc_bih, const float* __restrict__ enc_bhh,
            const float* __restrict__ dec_Wih,
            const float* __restrict__ dec_bih, const float* __restrict__ dec_bhh,
            const float* __restrict__ Wd_b, const float* __restrict__ vd_w,
            const float* __restrict__ fc_w, const float* __restrict__ fc_b,
            const char* __restrict__ ws8, float* __restrict__ out) {
  const short* f16  = (const short*)ws8;
  const i32x4* enc8 = (const i32x4*)(ws8 + WENC8_B);
  const i32x4* dec8 = (const i32x4*)(ws8 + WDEC8_B);
  const float* senc = (const float*)(ws8 + SENC_B);
  const float* sdec = (const float*)(ws8 + SDEC_B);

  __shared__ __align__(16) char  s_A8[16][272];   // gates A i8 (rows 0-1 real)
  __shared__ __align__(16) short s_Ahc[16][264];  // base/dc/proj A bf16 [h;c]
  __shared__ short s_projT[BB][64][65];           // enc_proj^T bf16
  __shared__ short s_encht[BB][128][66];          // enc_hiddens [r][j][t] bf16
  __shared__ float s_gates[BB][512];
  __shared__ float s_base[BB][64];                // enc: base ; dec: dc
  __shared__ float s_beta[BB][64];
  __shared__ float s_xr[BB];
  __shared__ float2 s_wv[64];                     // (w_feat[k], ve_w[k])
  __shared__ float s_web[64], s_vd[64], s_wdb[64];
  __shared__ float s_scl[512];                    // enc: senc | dec: sdec
  __shared__ float s_bias[1024];                  // enc: [encb,-] | dec: [decb,dwih]

  const int tid  = threadIdx.x;
  const int lane = tid & 63;
  const int w    = tid >> 6;        // wave 0..7 ; waves 0-1 own rows 0-1
  const int b0   = blockIdx.x * BB;

  // ---- init ----
  if (tid < 64) {
    s_wv[tid]  = make_float2(We_w[tid * 257 + 256], ve_w[tid]);
    s_web[tid] = We_b[tid];
    s_vd[tid]  = vd_w[tid];
    s_wdb[tid] = Wd_b[tid];
  }
  s_scl[tid]  = senc[tid];
  s_bias[tid] = enc_bih[tid] + enc_bhh[tid];      // encb
  for (int i = tid; i < (16 * 272) / 4; i += 512) ((int*)s_A8)[i] = 0;
  for (int i = tid; i < (16 * 264) / 2; i += 512) ((int*)s_Ahc)[i] = 0;
  if (tid < BB * 64) s_base[tid >> 6][tid & 63] = We_b[tid & 63];  // base_0
  // fc weights -> registers (used by waves 0-1 in decoder)
  const float fcw0 = fc_w[lane],       fcw1 = fc_w[64 + lane];
  const float fcw2 = fc_w[128 + lane], fcw3 = fc_w[192 + lane];
  const float fcwy = fc_w[256 + lane];
  const float fb0  = fc_b[0];

  // ---- register-resident weights ----
  i32x4 wg[4][4];                       // enc gates i8, nt = w + 8i
#pragma unroll
  for (int kt = 0; kt < 4; ++kt)
#pragma unroll
    for (int i = 0; i < 4; ++i)
      wg[kt][i] = enc8[(kt * 32 + (w + 8 * i)) * 64 + lane];
  bf16x8 wb[8], wp[4];
  if (w < 4) {
#pragma unroll
    for (int kt = 0; kt < 8; ++kt)
      wb[kt] = *(const bf16x8*)(f16 + WHS_E + ((kt * 4 + w) * 64 + lane) * 8);
  } else {
#pragma unroll
    for (int kt = 0; kt < 4; ++kt)
      wp[kt] = *(const bf16x8*)(f16 + WDENC_E + ((kt * 4 + (w - 4)) * 64 + lane) * 8);
  }

  // per-row state (waves 0-1): features j0=lane, j1=lane+64
  float h0 = 0.f, c0 = 0.f, h1 = 0.f, c1 = 0.f;
  float x0 = 0.f, x1 = 0.f, xi = 0.f;
  const float* Xr = X + (size_t)(b0 + (w & 1)) * T_ * D_;
  if (w < BB) {
    x0 = Xr[lane]; x1 = Xr[64 + lane];
    xi = 6.f * cosf((2 * (lane >> 3) + 1) * 0.19634954084936207f);  // node
  }
  __syncthreads();

  // ====================== encoder ======================
  for (int t = 0; t < T_; ++t) {
    // ---- P_A: input attention, in-wave, waves 0-1 (row = w) ----
    if (w < BB) {
      float x0n = 0.f, x1n = 0.f;
      if (t < T_ - 1) { x0n = Xr[(t + 1) * D_ + lane]; x1n = Xr[(t + 1) * D_ + 64 + lane]; }
      const int kc = lane & 7;
      float p = 0.f;
      const float4* wvp = (const float4*)&s_wv[kc * 8];
      const float4* bp  = (const float4*)&s_base[w][kc * 8];
      float4 bA = bp[0], bB = bp[1];
#pragma unroll
      for (int q = 0; q < 4; ++q) {
        float4 wv = wvp[q];
        float bb0 = (q < 2) ? ((q & 1) ? bA.z : bA.x) : ((q & 1) ? bB.z : bB.x);
        float bb1 = (q < 2) ? ((q & 1) ? bA.w : bA.y) : ((q & 1) ? bB.w : bB.y);
        p += wv.y * tanh_acc(fmaf(xi, wv.x, bb0));
        p += wv.w * tanh_acc(fmaf(xi, wv.z, bb1));
      }
      p += __shfl_xor(p, 1, 64); p += __shfl_xor(p, 2, 64); p += __shfl_xor(p, 4, 64);
      float f0 = __shfl(p,  0, 64), f1 = __shfl(p,  8, 64);
      float f2 = __shfl(p, 16, 64), f3 = __shfl(p, 24, 64);
      float f4 = __shfl(p, 32, 64), f5 = __shfl(p, 40, 64);
      float f6 = __shfl(p, 48, 64), f7 = __shfl(p, 56, 64);
      float sc0, sc1;
      {
        const float xb[8] = { 5.884711682f, 4.988817674f, 3.333421398f, 1.170541932f,
                             -1.170541932f, -3.333421398f, -4.988817674f, -5.884711682f};
        const float wbar[8] = { 0.1950903220f, -0.5555702330f, 0.8314696123f, -0.9807852804f,
                                0.9807852804f, -0.8314696123f, 0.5555702330f, -0.1950903220f};
        float u0 = fminf(fmaxf(x0, -6.f), 6.f), u1 = fminf(fmaxf(x1, -6.f), 6.f);
        float n0 = 0.f, d0 = 0.f, n1 = 0.f, d1 = 0.f;
        float fv[8] = {f0, f1, f2, f3, f4, f5, f6, f7};
#pragma unroll
        for (int i = 0; i < 8; ++i) {
          float dd0 = u0 - xb[i]; dd0 = copysignf(fmaxf(fabsf(dd0), 1e-5f), dd0);
          float dd1 = u1 - xb[i]; dd1 = copysignf(fmaxf(fabsf(dd1), 1e-5f), dd1);
          float t0 = wbar[i] * frcp(dd0), t1 = wbar[i] * frcp(dd1);
          n0 = fmaf(t0, fv[i], n0); d0 += t0;
          n1 = fmaf(t1, fv[i], n1); d1 += t1;
        }
        sc0 = n0 * frcp(d0); sc1 = n1 * frcp(d1);
      }
      float e0 = fexp2(sc0 * LOG2E), e1 = fexp2(sc1 * LOG2E);  // |sc|<=sum|ve|~2.6
      float sum = wsum64(e0 + e1);
      float mx  = wmax64(fmaxf(e0 * fabsf(x0), e1 * fabsf(x1)));
      float inv = mx > 0.f ? 127.f * frcp(mx) : 0.f;
      s_A8[w][lane]      = (char)(int)rintf(x0 * e0 * inv);
      s_A8[w][64 + lane] = (char)(int)rintf(x1 * e1 * inv);
      if (lane == 0) s_xr[w] = mx * frcp(127.f * sum);
      x0 = x0n; x1 = x1n;
    }
    __syncthreads();                                            // B1
    // ---- P_G: gates i8 GEMM, all 8 waves, weights in registers ----
    {
      i32x4 a0 = *(const i32x4*)&s_A8[lane & 15][  0 + ((lane >> 4) << 4)];
      i32x4 a1 = *(const i32x4*)&s_A8[lane & 15][ 64 + ((lane >> 4) << 4)];
      i32x4 a2 = *(const i32x4*)&s_A8[lane & 15][128 + ((lane >> 4) << 4)];
      i32x4 a3 = *(const i32x4*)&s_A8[lane & 15][192 + ((lane >> 4) << 4)];
      i32x4 ax[4], ah[4];
#pragma unroll
      for (int i = 0; i < 4; ++i) {
        i32x4 z = {0, 0, 0, 0};
        ax[i] = MFMAI8(a1, wg[1][i], MFMAI8(a0, wg[0][i], z));
        ah[i] = MFMAI8(a3, wg[3][i], MFMAI8(a2, wg[2][i], z));
      }
      if (lane < 16) {
        float sx0 = s_xr[0], sx1 = s_xr[1];
#pragma unroll
        for (int i = 0; i < 4; ++i) {
          int col = (w + 8 * i) * 16 + lane;
          float se = s_scl[col];
          s_gates[0][col] = se * fmaf(sx0, (float)ax[i][0], C127 * (float)ah[i][0]);
          s_gates[1][col] = se * fmaf(sx1, (float)ax[i][1], C127 * (float)ah[i][1]);
        }
      }
    }
    __syncthreads();                                            // B2
    // ---- P_E: LSTM epilogue, in-wave, waves 0-1 (2 features/lane) ----
    if (w < BB) {
      float gi0 = s_gates[w][lane]       + s_bias[lane];
      float gf0 = s_gates[w][lane + 128] + s_bias[lane + 128];
      float gg0 = s_gates[w][lane + 256] + s_bias[lane + 256];
      float go0 = s_gates[w][lane + 384] + s_bias[lane + 384];
      float gi1 = s_gates[w][lane + 64]  + s_bias[lane + 64];
      float gf1 = s_gates[w][lane + 192] + s_bias[lane + 192];
      float gg1 = s_gates[w][lane + 320] + s_bias[lane + 320];
      float go1 = s_gates[w][lane + 448] + s_bias[lane + 448];
      c0 = sigm(gf0) * c0 + sigm(gi0) * tanh_acc(gg0);
      h0 = sigm(go0) * tanh_acc(c0);
      c1 = sigm(gf1) * c1 + sigm(gi1) * tanh_acc(gg1);
      h1 = sigm(go1) * tanh_acc(c1);
      s_Ahc[w][lane]        = f2b(h0);
      s_Ahc[w][lane + 64]   = f2b(h1);
      s_Ahc[w][lane + 128]  = f2b(c0);
      s_Ahc[w][lane + 192]  = f2b(c1);
      s_A8[w][128 + lane]      = (char)(int)rintf(h0 * 127.f);
      s_A8[w][128 + lane + 64] = (char)(int)rintf(h1 * 127.f);
      s_encht[w][lane][t]      = f2b(h0);
      s_encht[w][lane + 64][t] = f2b(h1);
    }
    __syncthreads();                                            // B3
    // ---- P_B: base_{t+1} (waves 0-3) | proj_t (waves 4-7), B in regs ----
    if (w < 4) {
      f32x4 acc = {0.f, 0.f, 0.f, 0.f};
#pragma unroll
      for (int kt = 0; kt < 8; ++kt) {
        bf16x8 a = *(const bf16x8*)&s_Ahc[lane & 15][kt * 32 + ((lane >> 4) << 3)];
        acc = MFMA16(a, wb[kt], acc);
      }
      if (lane < 16) {
        int col = w * 16 + lane; float bias = s_web[col];
#pragma unroll
        for (int r = 0; r < BB; ++r) s_base[r][col] = acc[r] + bias;
      }
    } else {
      f32x4 acc = {0.f, 0.f, 0.f, 0.f};
#pragma unroll
      for (int kt = 0; kt < 4; ++kt) {
        bf16x8 a = *(const bf16x8*)&s_Ahc[lane & 15][kt * 32 + ((lane >> 4) << 3)];
        acc = MFMA16(a, wp[kt], acc);
      }
      if (lane < 16) {
        int katt = (w - 4) * 16 + lane;
#pragma unroll
        for (int r = 0; r < BB; ++r) s_projT[r][katt][t] = f2b(acc[r]);
      }
    }
    __syncthreads();                                            // B4
  }

  // ====================== decoder ======================
  // rewrite alias regions (encoder reads done: B3/B4 above)
  s_scl[tid]  = sdec[tid];
  s_bias[tid] = dec_bih[tid] + dec_bhh[tid];      // decb
  s_bias[512 + tid] = dec_Wih[tid];               // dwih
  if (tid < BB * 128) {
    int r = tid >> 7, j = tid & 127;
    s_Ahc[r][j] = 0; s_Ahc[r][128 + j] = 0; s_A8[r][j] = 0;
  }
  i32x4 wdg[2][8];                      // dec gates i8 (waves 4-7), nt=(w-4)*8+i
  bf16x8 wdc[8];                        // dc bf16 (waves 0-3)
  float yp = 0.f, yhd = 0.f;
  if (w >= 4) {
#pragma unroll
    for (int kt = 0; kt < 2; ++kt)
#pragma unroll
      for (int i = 0; i < 8; ++i)
        wdg[kt][i] = dec8[(kt * 32 + ((w - 4) * 8 + i)) * 64 + lane];
  } else {
#pragma unroll
    for (int kt = 0; kt < 8; ++kt)
      wdc[kt] = *(const bf16x8*)(f16 + WDDC_E + ((kt * 4 + w) * 64 + lane) * 8);
  }
  if (w < BB) {
    yp = y_hist[(b0 + w) * T_ + (T_ - 1)];
    float pp = fcwy * y_hist[(b0 + w) * T_ + lane];
    yhd = wsum64(pp) + fb0;
  }
  float dd0 = 0.f, dc0 = 0.f, dd1 = 0.f, dc1 = 0.f;   // d, cc (2 feats/lane)
  __syncthreads();

  for (int hs = 0; hs < HOR_; ++hs) {
    // ---- P_dG: dec gates i8 (waves 4-7) | dc bf16 (waves 0-3) ----
    if (w >= 4) {
      i32x4 a0 = *(const i32x4*)&s_A8[lane & 15][ 0 + ((lane >> 4) << 4)];
      i32x4 a1 = *(const i32x4*)&s_A8[lane & 15][64 + ((lane >> 4) << 4)];
#pragma unroll
      for (int i = 0; i < 8; ++i) {
        i32x4 z = {0, 0, 0, 0};
        i32x4 ac = MFMAI8(a1, wdg[1][i], MFMAI8(a0, wdg[0][i], z));
        if (lane < 16) {
          int col = ((w - 4) * 8 + i) * 16 + lane;
          float sd = s_scl[col] * C127;
#pragma unroll
          for (int r = 0; r < BB; ++r) s_gates[r][col] = sd * (float)ac[r];
        }
      }
    } else {
      f32x4 acc = {0.f, 0.f, 0.f, 0.f};
#pragma unroll
      for (int kt = 0; kt < 8; ++kt) {
        bf16x8 a = *(const bf16x8*)&s_Ahc[lane & 15][kt * 32 + ((lane >> 4) << 3)];
        acc = MFMA16(a, wdc[kt], acc);
      }
      if (lane < 16) {
        int col = w * 16 + lane; float bias = s_wdb[col];
#pragma unroll
        for (int r = 0; r < BB; ++r) s_base[r][col] = acc[r] + bias;
      }
    }
    __syncthreads();                                            // B1
    // ---- P_dA: attention + context + epilogue + fc, in-wave (waves 0-1) ----
    if (w < BB) {
      float s = 0.f;
#pragma unroll 8
      for (int k = 0; k < 64; ++k)
        s += s_vd[k] * tanh_acc(b2f(s_projT[w][k][lane]) + s_base[w][k]);
      float e = fexp2(s * LOG2E);
      float ssum = wsum64(e);
      s_beta[w][lane] = e * frcp(ssum);
      float cx0 = 0.f, cx1 = 0.f;
      const short* e0p = &s_encht[w][lane][0];
      const short* e1p = &s_encht[w][lane + 64][0];
#pragma unroll 8
      for (int tp = 0; tp < 64; ++tp) {
        float bta = s_beta[w][tp];
        cx0 = fmaf(bta, b2f(e0p[tp]), cx0);
        cx1 = fmaf(bta, b2f(e1p[tp]), cx1);
      }
      float gi0 = s_gates[w][lane]       + s_bias[lane]       + yp * s_bias[512 + lane];
      float gf0 = s_gates[w][lane + 128] + s_bias[lane + 128] + yp * s_bias[640 + lane];
      float gg0 = s_gates[w][lane + 256] + s_bias[lane + 256] + yp * s_bias[768 + lane];
      float go0 = s_gates[w][lane + 384] + s_bias[lane + 384] + yp * s_bias[896 + lane];
      float gi1 = s_gates[w][lane + 64]  + s_bias[lane + 64]  + yp * s_bias[576 + lane];
      float gf1 = s_gates[w][lane + 192] + s_bias[lane + 192] + yp * s_bias[704 + lane];
      float gg1 = s_gates[w][lane + 320] + s_bias[lane + 320] + yp * s_bias[832 + lane];
      float go1 = s_gates[w][lane + 448] + s_bias[lane + 448] + yp * s_bias[960 + lane];
      dc0 = sigm(gf0) * dc0 + sigm(gi0) * tanh_acc(gg0);
      dd0 = sigm(go0) * tanh_acc(dc0);
      dc1 = sigm(gf1) * dc1 + sigm(gi1) * tanh_acc(gg1);
      dd1 = sigm(go1) * tanh_acc(dc1);
      float pf = fcw0 * dd0 + fcw1 * dd1 + fcw2 * cx0 + fcw3 * cx1;
      pf = wsum64(pf);
      float o = pf + yhd;
      if (lane == 0) out[(b0 + w) * HOR_ + hs] = o;
      yp = o;
      s_Ahc[w][lane]       = f2b(dd0);
      s_Ahc[w][lane + 64]  = f2b(dd1);
      s_Ahc[w][lane + 128] = f2b(dc0);
      s_Ahc[w][lane + 192] = f2b(dc1);
      s_A8[w][lane]      = (char)(int)rintf(dd0 * 127.f);
      s_A8[w][lane + 64] = (char)(int)rintf(dd1 * 127.f);
    }
    __syncthreads();                                            // B2
  }
}

extern "C" void kernel_launch(void* const* d_in, const int* in_sizes, int n_in,
                              void* d_out, int out_size, void* d_ws, size_t ws_size,
                              hipStream_t stream) {
  (void)in_sizes; (void)n_in; (void)out_size; (void)ws_size;
  const float* X       = (const float*)d_in[0];
  const float* y_hist  = (const float*)d_in[1];
  const float* We_w    = (const float*)d_in[2];
  const float* We_b    = (const float*)d_in[3];
  const float* ve_w    = (const float*)d_in[4];
  // d_in[5] = ve_b : softmax-invariant, unused
  const float* enc_Wih = (const float*)d_in[6];
  const float* enc_Whh = (const float*)d_in[7];
  const float* enc_bih = (const float*)d_in[8];
  const float* enc_bhh = (const float*)d_in[9];
  const float* dec_Wih = (const float*)d_in[10];
  const float* dec_Whh = (const float*)d_in[11];
  const float* dec_bih = (const float*)d_in[12];
  const float* dec_bhh = (const float*)d_in[13];
  const float* Wd_w    = (const float*)d_in[14];
  const float* Wd_b    = (const float*)d_in[15];
  const float* vd_w    = (const float*)d_in[16];
  // d_in[17] = vd_b : softmax-invariant, unused
  const float* fc_w    = (const float*)d_in[18];
  const float* fc_b    = (const float*)d_in[19];

  char* ws8  = (char*)d_ws;
  float* out = (float*)d_out;

  prep_bf<<<160, 256, 0, stream>>>(We_w, Wd_w, ws8);
  prep_q <<<256, 256, 0, stream>>>(enc_Wih, enc_Whh, dec_Whh, ws8);
  da_rnn <<<B_ / BB, 512, 0, stream>>>(X, y_hist, We_w, We_b, ve_w,
                                       enc_bih, enc_bhh, dec_Wih, dec_bih, dec_bhh,
                                       Wd_b, vd_w, fc_w, fc_b, ws8, out);
}

// Round 8
// 573.743 us; speedup vs baseline: 1.1908x; 1.1908x over previous
//
#include <hip/hip_runtime.h>
#include <hip/hip_bf16.h>

// DA-RNN persistent kernel, round 8 = round 7 with the launch-bounds fix.
// R7 lesson (measured): __launch_bounds__(512,4) => 64-VGPR cap (allocator
// treats arg as blocks/CU for 512-thread blocks) => register weights spilled,
// 117MB scratch writes, 605us. R8: __launch_bounds__(512,2) => 128-VGPR cap
// (R6 fit in 100), keep R7's 76KB LDS which already achieved 2 blocks/CU
// (Occupancy 45%) -> two co-resident blocks overlap barrier/latency chains.

#define B_    1024
#define T_    64
#define D_    128
#define H_    128
#define HOR_  24
#define ATT_  64
#define BB    2
#define LOG2E 1.4426950408889634f
#define C127  (1.f/127.f)

typedef float f32x4  __attribute__((ext_vector_type(4)));
typedef short bf16x8 __attribute__((ext_vector_type(8)));
typedef int   i32x4  __attribute__((ext_vector_type(4)));

#define MFMA16(a,b,c) __builtin_amdgcn_mfma_f32_16x16x32_bf16((a),(b),(c),0,0,0)
#define MFMAI8(a,b,c) __builtin_amdgcn_mfma_i32_16x16x64_i8((a),(b),(c),0,0,0)

// ---- workspace layout (same packing as R5/R6/R7) ----
#define WHS_E    0        // base GEMM  B bf16: kt0..7, nt0..3  (16384 el)
#define WDDC_E   16384    // dc GEMM    B bf16: kt0..7, nt0..3  (16384 el)
#define WDENC_E  32768    // proj GEMM  B bf16: kt0..3, nt0..3  ( 8192 el)
#define WENC8_B  81920    // i8 enc gates B: [kt4][nt32][lane64][16] (131072 B)
#define WDEC8_B  212992   // i8 dec gates B: [kt2][nt32][lane64][16] ( 65536 B)
#define SENC_B   278528   // 512 f32 per-col scales (enc)
#define SDEC_B   280576   // 512 f32 per-col scales (dec)

__device__ __forceinline__ short f2b(float f) {        // fp32 -> bf16 RNE
  union { float f; unsigned u; } c; c.f = f;
  unsigned r = c.u + 0x7fffu + ((c.u >> 16) & 1u);
  return (short)(r >> 16);
}
__device__ __forceinline__ float b2f(short s) {
  union { unsigned u; float f; } c; c.u = ((unsigned)(unsigned short)s) << 16;
  return c.f;
}
__device__ __forceinline__ float fexp2(float x) { return __builtin_amdgcn_exp2f(x); }
__device__ __forceinline__ float frcp (float x) { return __builtin_amdgcn_rcpf(x); }
__device__ __forceinline__ float tanh_acc(float x) {   // 1 - 2/(1+e^{2x})
  float e = fexp2(x * 2.885390081777927f);
  return 1.f - 2.f * frcp(1.f + e);
}
__device__ __forceinline__ float sigm(float x) {
  return frcp(1.f + fexp2(-LOG2E * x));
}
__device__ __forceinline__ float wsum64(float v) {
#pragma unroll
  for (int o = 32; o > 0; o >>= 1) v += __shfl_xor(v, o, 64);
  return v;
}
__device__ __forceinline__ float wmax64(float v) {
#pragma unroll
  for (int o = 32; o > 0; o >>= 1) v = fmaxf(v, __shfl_xor(v, o, 64));
  return v;
}

// ---- prep1: bf16 B-frags (base / dc / proj), one element per thread ----
__global__ void prep_bf(const float* __restrict__ We_w,
                        const float* __restrict__ Wd_w,
                        char* __restrict__ ws8) {
  int e = blockIdx.x * 256 + threadIdx.x;
  if (e >= 40960) return;
  short* f16 = (short*)ws8;
  int region = e >> 14;                  // 0=WHS 1=WDDC 2=WDENC
  int er = e & 16383;
  int fi = er >> 9, li = (er >> 3) & 63, jq = er & 7;
  int kt = fi >> 2, nt = fi & 3;
  int k = kt * 32 + ((li >> 4) << 3) + jq, n = nt * 16 + (li & 15);
  float v;
  if (region == 0)      v = We_w[n * 257 + k];
  else if (region == 1) v = (k < 128) ? Wd_w[n * 384 + 128 + k]
                                      : Wd_w[n * 384 + 256 + (k - 128)];
  else                  v = Wd_w[n * 384 + k];
  f16[e] = f2b(v);
}

// ---- prep2: i8 quantized gates weights, one wave per column ----
__global__ void prep_q(const float* __restrict__ enc_Wih,
                       const float* __restrict__ enc_Whh,
                       const float* __restrict__ dec_Whh,
                       char* __restrict__ ws8) {
  int gw = (blockIdx.x * 256 + threadIdx.x) >> 6;
  int lane = threadIdx.x & 63;
  if (gw < 512) {                        // encoder col, K=256
    int n = gw;
    float v[4]; float m = 0.f;
#pragma unroll
    for (int q = 0; q < 4; ++q) {
      int k = lane * 4 + q;
      v[q] = (k < 128) ? enc_Wih[n * 128 + k] : enc_Whh[n * 128 + (k - 128)];
      m = fmaxf(m, fabsf(v[q]));
    }
    m = wmax64(m);
    if (lane == 0) ((float*)(ws8 + SENC_B))[n] = m * C127;
    float inv = m > 0.f ? 127.f / m : 0.f;
    char* dst = ws8 + WENC8_B;
#pragma unroll
    for (int q = 0; q < 4; ++q) {
      int k = lane * 4 + q;
      int kt = k >> 6, grp = (k >> 4) & 3, b = k & 15, l16 = (n & 15) | (grp << 4);
      dst[((kt * 32 + (n >> 4)) * 64 + l16) * 16 + b] = (char)(int)rintf(v[q] * inv);
    }
  } else if (gw < 1024) {                // decoder col, K=128
    int n = gw - 512;
    float v[2]; float m = 0.f;
#pragma unroll
    for (int q = 0; q < 2; ++q) {
      int k = lane * 2 + q;
      v[q] = dec_Whh[n * 128 + k];
      m = fmaxf(m, fabsf(v[q]));
    }
    m = wmax64(m);
    if (lane == 0) ((float*)(ws8 + SDEC_B))[n] = m * C127;
    float inv = m > 0.f ? 127.f / m : 0.f;
    char* dst = ws8 + WDEC8_B;
#pragma unroll
    for (int q = 0; q < 2; ++q) {
      int k = lane * 2 + q;
      int kt = k >> 6, grp = (k >> 4) & 3, b = k & 15, l16 = (n & 15) | (grp << 4);
      dst[((kt * 32 + (n >> 4)) * 64 + l16) * 16 + b] = (char)(int)rintf(v[q] * inv);
    }
  }
}

__global__ __launch_bounds__(512, 2)
void da_rnn(const float* __restrict__ X, const float* __restrict__ y_hist,
            const float* __restrict__ We_w, const float* __restrict__ We_b,
            const float* __restrict__ ve_w,
            const float* __restrict__ enc_bih, const float* __restrict__ enc_bhh,
            const float* __restrict__ dec_Wih,
            const float* __restrict__ dec_bih, const float* __restrict__ dec_bhh,
            const float* __restrict__ Wd_b, const float* __restrict__ vd_w,
            const float* __restrict__ fc_w, const float* __restrict__ fc_b,
            const char* __restrict__ ws8, float* __restrict__ out) {
  const short* f16  = (const short*)ws8;
  const i32x4* enc8 = (const i32x4*)(ws8 + WENC8_B);
  const i32x4* dec8 = (const i32x4*)(ws8 + WDEC8_B);
  const float* senc = (const float*)(ws8 + SENC_B);
  const float* sdec = (const float*)(ws8 + SDEC_B);

  __shared__ __align__(16) char  s_A8[16][272];   // gates A i8 (rows 0-1 real)
  __shared__ __align__(16) short s_Ahc[16][264];  // base/dc/proj A bf16 [h;c]
  __shared__ short s_projT[BB][64][65];           // enc_proj^T bf16
  __shared__ short s_encht[BB][128][66];          // enc_hiddens [r][j][t] bf16
  __shared__ float s_gates[BB][512];
  __shared__ float s_base[BB][64];                // enc: base ; dec: dc
  __shared__ float s_beta[BB][64];
  __shared__ float s_xr[BB];
  __shared__ float2 s_wv[64];                     // (w_feat[k], ve_w[k])
  __shared__ float s_web[64], s_vd[64], s_wdb[64];
  __shared__ float s_scl[512];                    // enc: senc | dec: sdec
  __shared__ float s_bias[1024];                  // enc: [encb,-] | dec: [decb,dwih]

  const int tid  = threadIdx.x;
  const int lane = tid & 63;
  const int w    = tid >> 6;        // wave 0..7 ; waves 0-1 own rows 0-1
  const int b0   = blockIdx.x * BB;

  // ---- init ----
  if (tid < 64) {
    s_wv[tid]  = make_float2(We_w[tid * 257 + 256], ve_w[tid]);
    s_web[tid] = We_b[tid];
    s_vd[tid]  = vd_w[tid];
    s_wdb[tid] = Wd_b[tid];
  }
  s_scl[tid]  = senc[tid];
  s_bias[tid] = enc_bih[tid] + enc_bhh[tid];      // encb
  for (int i = tid; i < (16 * 272) / 4; i += 512) ((int*)s_A8)[i] = 0;
  for (int i = tid; i < (16 * 264) / 2; i += 512) ((int*)s_Ahc)[i] = 0;
  if (tid < BB * 64) s_base[tid >> 6][tid & 63] = We_b[tid & 63];  // base_0
  // fc weights -> registers (used by waves 0-1 in decoder)
  const float fcw0 = fc_w[lane],       fcw1 = fc_w[64 + lane];
  const float fcw2 = fc_w[128 + lane], fcw3 = fc_w[192 + lane];
  const float fcwy = fc_w[256 + lane];
  const float fb0  = fc_b[0];

  // ---- register-resident weights ----
  i32x4 wg[4][4];                       // enc gates i8, nt = w + 8i
#pragma unroll
  for (int kt = 0; kt < 4; ++kt)
#pragma unroll
    for (int i = 0; i < 4; ++i)
      wg[kt][i] = enc8[(kt * 32 + (w + 8 * i)) * 64 + lane];
  bf16x8 wb[8], wp[4];
  if (w < 4) {
#pragma unroll
    for (int kt = 0; kt < 8; ++kt)
      wb[kt] = *(const bf16x8*)(f16 + WHS_E + ((kt * 4 + w) * 64 + lane) * 8);
  } else {
#pragma unroll
    for (int kt = 0; kt < 4; ++kt)
      wp[kt] = *(const bf16x8*)(f16 + WDENC_E + ((kt * 4 + (w - 4)) * 64 + lane) * 8);
  }

  // per-row state (waves 0-1): features j0=lane, j1=lane+64
  float h0 = 0.f, c0 = 0.f, h1 = 0.f, c1 = 0.f;
  float x0 = 0.f, x1 = 0.f, xi = 0.f;
  const float* Xr = X + (size_t)(b0 + (w & 1)) * T_ * D_;
  if (w < BB) {
    x0 = Xr[lane]; x1 = Xr[64 + lane];
    xi = 6.f * cosf((2 * (lane >> 3) + 1) * 0.19634954084936207f);  // node
  }
  __syncthreads();

  // ====================== encoder ======================
  for (int t = 0; t < T_; ++t) {
    // ---- P_A: input attention, in-wave, waves 0-1 (row = w) ----
    if (w < BB) {
      float x0n = 0.f, x1n = 0.f;
      if (t < T_ - 1) { x0n = Xr[(t + 1) * D_ + lane]; x1n = Xr[(t + 1) * D_ + 64 + lane]; }
      const int kc = lane & 7;
      float p = 0.f;
      const float4* wvp = (const float4*)&s_wv[kc * 8];
      const float4* bp  = (const float4*)&s_base[w][kc * 8];
      float4 bA = bp[0], bB = bp[1];
#pragma unroll
      for (int q = 0; q < 4; ++q) {
        float4 wv = wvp[q];
        float bb0 = (q < 2) ? ((q & 1) ? bA.z : bA.x) : ((q & 1) ? bB.z : bB.x);
        float bb1 = (q < 2) ? ((q & 1) ? bA.w : bA.y) : ((q & 1) ? bB.w : bB.y);
        p += wv.y * tanh_acc(fmaf(xi, wv.x, bb0));
        p += wv.w * tanh_acc(fmaf(xi, wv.z, bb1));
      }
      p += __shfl_xor(p, 1, 64); p += __shfl_xor(p, 2, 64); p += __shfl_xor(p, 4, 64);
      float f0 = __shfl(p,  0, 64), f1 = __shfl(p,  8, 64);
      float f2 = __shfl(p, 16, 64), f3 = __shfl(p, 24, 64);
      float f4 = __shfl(p, 32, 64), f5 = __shfl(p, 40, 64);
      float f6 = __shfl(p, 48, 64), f7 = __shfl(p, 56, 64);
      float sc0, sc1;
      {
        const float xb[8] = { 5.884711682f, 4.988817674f, 3.333421398f, 1.170541932f,
                             -1.170541932f, -3.333421398f, -4.988817674f, -5.884711682f};
        const float wbar[8] = { 0.1950903220f, -0.5555702330f, 0.8314696123f, -0.9807852804f,
                                0.9807852804f, -0.8314696123f, 0.5555702330f, -0.1950903220f};
        float u0 = fminf(fmaxf(x0, -6.f), 6.f), u1 = fminf(fmaxf(x1, -6.f), 6.f);
        float n0 = 0.f, d0 = 0.f, n1 = 0.f, d1 = 0.f;
        float fv[8] = {f0, f1, f2, f3, f4, f5, f6, f7};
#pragma unroll
        for (int i = 0; i < 8; ++i) {
          float dd0 = u0 - xb[i]; dd0 = copysignf(fmaxf(fabsf(dd0), 1e-5f), dd0);
          float dd1 = u1 - xb[i]; dd1 = copysignf(fmaxf(fabsf(dd1), 1e-5f), dd1);
          float t0 = wbar[i] * frcp(dd0), t1 = wbar[i] * frcp(dd1);
          n0 = fmaf(t0, fv[i], n0); d0 += t0;
          n1 = fmaf(t1, fv[i], n1); d1 += t1;
        }
        sc0 = n0 * frcp(d0); sc1 = n1 * frcp(d1);
      }
      float e0 = fexp2(sc0 * LOG2E), e1 = fexp2(sc1 * LOG2E);  // |sc|<=sum|ve|~2.6
      float sum = wsum64(e0 + e1);
      float mx  = wmax64(fmaxf(e0 * fabsf(x0), e1 * fabsf(x1)));
      float inv = mx > 0.f ? 127.f * frcp(mx) : 0.f;
      s_A8[w][lane]      = (char)(int)rintf(x0 * e0 * inv);
      s_A8[w][64 + lane] = (char)(int)rintf(x1 * e1 * inv);
      if (lane == 0) s_xr[w] = mx * frcp(127.f * sum);
      x0 = x0n; x1 = x1n;
    }
    __syncthreads();                                            // B1
    // ---- P_G: gates i8 GEMM, all 8 waves, weights in registers ----
    {
      i32x4 a0 = *(const i32x4*)&s_A8[lane & 15][  0 + ((lane >> 4) << 4)];
      i32x4 a1 = *(const i32x4*)&s_A8[lane & 15][ 64 + ((lane >> 4) << 4)];
      i32x4 a2 = *(const i32x4*)&s_A8[lane & 15][128 + ((lane >> 4) << 4)];
      i32x4 a3 = *(const i32x4*)&s_A8[lane & 15][192 + ((lane >> 4) << 4)];
      i32x4 ax[4], ah[4];
#pragma unroll
      for (int i = 0; i < 4; ++i) {
        i32x4 z = {0, 0, 0, 0};
        ax[i] = MFMAI8(a1, wg[1][i], MFMAI8(a0, wg[0][i], z));
        ah[i] = MFMAI8(a3, wg[3][i], MFMAI8(a2, wg[2][i], z));
      }
      if (lane < 16) {
        float sx0 = s_xr[0], sx1 = s_xr[1];
#pragma unroll
        for (int i = 0; i < 4; ++i) {
          int col = (w + 8 * i) * 16 + lane;
          float se = s_scl[col];
          s_gates[0][col] = se * fmaf(sx0, (float)ax[i][0], C127 * (float)ah[i][0]);
          s_gates[1][col] = se * fmaf(sx1, (float)ax[i][1], C127 * (float)ah[i][1]);
        }
      }
    }
    __syncthreads();                                            // B2
    // ---- P_E: LSTM epilogue, in-wave, waves 0-1 (2 features/lane) ----
    if (w < BB) {
      float gi0 = s_gates[w][lane]       + s_bias[lane];
      float gf0 = s_gates[w][lane + 128] + s_bias[lane + 128];
      float gg0 = s_gates[w][lane + 256] + s_bias[lane + 256];
      float go0 = s_gates[w][lane + 384] + s_bias[lane + 384];
      float gi1 = s_gates[w][lane + 64]  + s_bias[lane + 64];
      float gf1 = s_gates[w][lane + 192] + s_bias[lane + 192];
      float gg1 = s_gates[w][lane + 320] + s_bias[lane + 320];
      float go1 = s_gates[w][lane + 448] + s_bias[lane + 448];
      c0 = sigm(gf0) * c0 + sigm(gi0) * tanh_acc(gg0);
      h0 = sigm(go0) * tanh_acc(c0);
      c1 = sigm(gf1) * c1 + sigm(gi1) * tanh_acc(gg1);
      h1 = sigm(go1) * tanh_acc(c1);
      s_Ahc[w][lane]        = f2b(h0);
      s_Ahc[w][lane + 64]   = f2b(h1);
      s_Ahc[w][lane + 128]  = f2b(c0);
      s_Ahc[w][lane + 192]  = f2b(c1);
      s_A8[w][128 + lane]      = (char)(int)rintf(h0 * 127.f);
      s_A8[w][128 + lane + 64] = (char)(int)rintf(h1 * 127.f);
      s_encht[w][lane][t]      = f2b(h0);
      s_encht[w][lane + 64][t] = f2b(h1);
    }
    __syncthreads();                                            // B3
    // ---- P_B: base_{t+1} (waves 0-3) | proj_t (waves 4-7), B in regs ----
    if (w < 4) {
      f32x4 acc = {0.f, 0.f, 0.f, 0.f};
#pragma unroll
      for (int kt = 0; kt < 8; ++kt) {
        bf16x8 a = *(const bf16x8*)&s_Ahc[lane & 15][kt * 32 + ((lane >> 4) << 3)];
        acc = MFMA16(a, wb[kt], acc);
      }
      if (lane < 16) {
        int col = w * 16 + lane; float bias = s_web[col];
#pragma unroll
        for (int r = 0; r < BB; ++r) s_base[r][col] = acc[r] + bias;
      }
    } else {
      f32x4 acc = {0.f, 0.f, 0.f, 0.f};
#pragma unroll
      for (int kt = 0; kt < 4; ++kt) {
        bf16x8 a = *(const bf16x8*)&s_Ahc[lane & 15][kt * 32 + ((lane >> 4) << 3)];
        acc = MFMA16(a, wp[kt], acc);
      }
      if (lane < 16) {
        int katt = (w - 4) * 16 + lane;
#pragma unroll
        for (int r = 0; r < BB; ++r) s_projT[r][katt][t] = f2b(acc[r]);
      }
    }
    __syncthreads();                                            // B4
  }

  // ====================== decoder ======================
  // rewrite alias regions (encoder reads done: B3/B4 above)
  s_scl[tid]  = sdec[tid];
  s_bias[tid] = dec_bih[tid] + dec_bhh[tid];      // decb
  s_bias[512 + tid] = dec_Wih[tid];               // dwih
  if (tid < BB * 128) {
    int r = tid >> 7, j = tid & 127;
    s_Ahc[r][j] = 0; s_Ahc[r][128 + j] = 0; s_A8[r][j] = 0;
  }
  i32x4 wdg[2][8];                      // dec gates i8 (waves 4-7), nt=(w-4)*8+i
  bf16x8 wdc[8];                        // dc bf16 (waves 0-3)
  float yp = 0.f, yhd = 0.f;
  if (w >= 4) {
#pragma unroll
    for (int kt = 0; kt < 2; ++kt)
#pragma unroll
      for (int i = 0; i < 8; ++i)
        wdg[kt][i] = dec8[(kt * 32 + ((w - 4) * 8 + i)) * 64 + lane];
  } else {
#pragma unroll
    for (int kt = 0; kt < 8; ++kt)
      wdc[kt] = *(const bf16x8*)(f16 + WDDC_E + ((kt * 4 + w) * 64 + lane) * 8);
  }
  if (w < BB) {
    yp = y_hist[(b0 + w) * T_ + (T_ - 1)];
    float pp = fcwy * y_hist[(b0 + w) * T_ + lane];
    yhd = wsum64(pp) + fb0;
  }
  float dd0 = 0.f, dc0 = 0.f, dd1 = 0.f, dc1 = 0.f;   // d, cc (2 feats/lane)
  __syncthreads();

  for (int hs = 0; hs < HOR_; ++hs) {
    // ---- P_dG: dec gates i8 (waves 4-7) | dc bf16 (waves 0-3) ----
    if (w >= 4) {
      i32x4 a0 = *(const i32x4*)&s_A8[lane & 15][ 0 + ((lane >> 4) << 4)];
      i32x4 a1 = *(const i32x4*)&s_A8[lane & 15][64 + ((lane >> 4) << 4)];
#pragma unroll
      for (int i = 0; i < 8; ++i) {
        i32x4 z = {0, 0, 0, 0};
        i32x4 ac = MFMAI8(a1, wdg[1][i], MFMAI8(a0, wdg[0][i], z));
        if (lane < 16) {
          int col = ((w - 4) * 8 + i) * 16 + lane;
          float sd = s_scl[col] * C127;
#pragma unroll
          for (int r = 0; r < BB; ++r) s_gates[r][col] = sd * (float)ac[r];
        }
      }
    } else {
      f32x4 acc = {0.f, 0.f, 0.f, 0.f};
#pragma unroll
      for (int kt = 0; kt < 8; ++kt) {
        bf16x8 a = *(const bf16x8*)&s_Ahc[lane & 15][kt * 32 + ((lane >> 4) << 3)];
        acc = MFMA16(a, wdc[kt], acc);
      }
      if (lane < 16) {
        int col = w * 16 + lane; float bias = s_wdb[col];
#pragma unroll
        for (int r = 0; r < BB; ++r) s_base[r][col] = acc[r] + bias;
      }
    }
    __syncthreads();                                            // B1
    // ---- P_dA: attention + context + epilogue + fc, in-wave (waves 0-1) ----
    if (w < BB) {
      float s = 0.f;
#pragma unroll 8
      for (int k = 0; k < 64; ++k)
        s += s_vd[k] * tanh_acc(b2f(s_projT[w][k][lane]) + s_base[w][k]);
      float e = fexp2(s * LOG2E);
      float ssum = wsum64(e);
      s_beta[w][lane] = e * frcp(ssum);
      float cx0 = 0.f, cx1 = 0.f;
      const short* e0p = &s_encht[w][lane][0];
      const short* e1p = &s_encht[w][lane + 64][0];
#pragma unroll 8
      for (int tp = 0; tp < 64; ++tp) {
        float bta = s_beta[w][tp];
        cx0 = fmaf(bta, b2f(e0p[tp]), cx0);
        cx1 = fmaf(bta, b2f(e1p[tp]), cx1);
      }
      float gi0 = s_gates[w][lane]       + s_bias[lane]       + yp * s_bias[512 + lane];
      float gf0 = s_gates[w][lane + 128] + s_bias[lane + 128] + yp * s_bias[640 + lane];
      float gg0 = s_gates[w][lane + 256] + s_bias[lane + 256] + yp * s_bias[768 + lane];
      float go0 = s_gates[w][lane + 384] + s_bias[lane + 384] + yp * s_bias[896 + lane];
      float gi1 = s_gates[w][lane + 64]  + s_bias[lane + 64]  + yp * s_bias[576 + lane];
      float gf1 = s_gates[w][lane + 192] + s_bias[lane + 192] + yp * s_bias[704 + lane];
      float gg1 = s_gates[w][lane + 320] + s_bias[lane + 320] + yp * s_bias[832 + lane];
      float go1 = s_gates[w][lane + 448] + s_bias[lane + 448] + yp * s_bias[960 + lane];
      dc0 = sigm(gf0) * dc0 + sigm(gi0) * tanh_acc(gg0);
      dd0 = sigm(go0) * tanh_acc(dc0);
      dc1 = sigm(gf1) * dc1 + sigm(gi1) * tanh_acc(gg1);
      dd1 = sigm(go1) * tanh_acc(dc1);
      float pf = fcw0 * dd0 + fcw1 * dd1 + fcw2 * cx0 + fcw3 * cx1;
      pf = wsum64(pf);
      float o = pf + yhd;
      if (lane == 0) out[(b0 + w) * HOR_ + hs] = o;
      yp = o;
      s_Ahc[w][lane]       = f2b(dd0);
      s_Ahc[w][lane + 64]  = f2b(dd1);
      s_Ahc[w][lane + 128] = f2b(dc0);
      s_Ahc[w][lane + 192] = f2b(dc1);
      s_A8[w][lane]      = (char)(int)rintf(dd0 * 127.f);
      s_A8[w][lane + 64] = (char)(int)rintf(dd1 * 127.f);
    }
    __syncthreads();                                            // B2
  }
}

extern "C" void kernel_launch(void* const* d_in, const int* in_sizes, int n_in,
                              void* d_out, int out_size, void* d_ws, size_t ws_size,
                              hipStream_t stream) {
  (void)in_sizes; (void)n_in; (void)out_size; (void)ws_size;
  const float* X       = (const float*)d_in[0];
  const float* y_hist  = (const float*)d_in[1];
  const float* We_w    = (const float*)d_in[2];
  const float* We_b    = (const float*)d_in[3];
  const float* ve_w    = (const float*)d_in[4];
  // d_in[5] = ve_b : softmax-invariant, unused
  const float* enc_Wih = (const float*)d_in[6];
  const float* enc_Whh = (const float*)d_in[7];
  const float* enc_bih = (const float*)d_in[8];
  const float* enc_bhh = (const float*)d_in[9];
  const float* dec_Wih = (const float*)d_in[10];
  const float* dec_Whh = (const float*)d_in[11];
  const float* dec_bih = (const float*)d_in[12];
  const float* dec_bhh = (const float*)d_in[13];
  const float* Wd_w    = (const float*)d_in[14];
  const float* Wd_b    = (const float*)d_in[15];
  const float* vd_w    = (const float*)d_in[16];
  // d_in[17] = vd_b : softmax-invariant, unused
  const float* fc_w    = (const float*)d_in[18];
  const float* fc_b    = (const float*)d_in[19];

  char* ws8  = (char*)d_ws;
  float* out = (float*)d_out;

  prep_bf<<<160, 256, 0, stream>>>(We_w, Wd_w, ws8);
  prep_q <<<256, 256, 0, stream>>>(enc_Wih, enc_Whh, dec_Whh, ws8);
  da_rnn <<<B_ / BB, 512, 0, stream>>>(X, y_hist, We_w, We_b, ve_w,
                                       enc_bih, enc_bhh, dec_Wih, dec_bih, dec_bhh,
                                       Wd_b, vd_w, fc_w, fc_b, ws8, out);
}

// Round 9
// 372.412 us; speedup vs baseline: 1.8345x; 1.5406x over previous
//
#include <hip/hip_runtime.h>
#include <hip/hip_bf16.h>

// DA-RNN persistent kernel, round 9 = R6 (best, 273us) + critical-path cuts.
// R8 proved 2 blocks/CU is blocked by VGPR+AGPR capacity -> stay 1 block/CU
// (BB=4, 256 blocks x 512 thr) and shorten the per-step chain:
//  - LSTM epilogue FUSED into the gates-GEMM wave: wave w's tiles {w,w+8,w+16,
//    w+24} are gates {i,f,g,o} for features w*16+lane, rows=reg for lanes<16 ->
//    epilogue runs in-register right after the MFMAs. c-state in registers.
//    s_gates round-trip + P_E phase + 1 barrier eliminated (4 -> 3 barriers).
//  - h-quant / encht writes deferred to next phase top (barrier-separated WAR;
//    h carried in regs) -- avoids intra-phase race on s_A8's h half.
//  - attention: 8 serial shuffle broadcasts -> LDS bounce (2x ds_read_b128).
//  - prep_bf + prep_q merged into one launch.

#define B_    1024
#define T_    64
#define D_    128
#define H_    128
#define HOR_  24
#define ATT_  64
#define BB    4
#define LOG2E 1.4426950408889634f
#define C127  (1.f/127.f)

typedef float f32x4  __attribute__((ext_vector_type(4)));
typedef short bf16x8 __attribute__((ext_vector_type(8)));
typedef int   i32x4  __attribute__((ext_vector_type(4)));

#define MFMA16(a,b,c) __builtin_amdgcn_mfma_f32_16x16x32_bf16((a),(b),(c),0,0,0)
#define MFMAI8(a,b,c) __builtin_amdgcn_mfma_i32_16x16x64_i8((a),(b),(c),0,0,0)

// ---- workspace layout (same packing as R5..R8) ----
#define WHS_E    0        // base GEMM  B bf16: kt0..7, nt0..3  (16384 el)
#define WDDC_E   16384    // dc GEMM    B bf16: kt0..7, nt0..3  (16384 el)
#define WDENC_E  32768    // proj GEMM  B bf16: kt0..3, nt0..3  ( 8192 el)
#define WENC8_B  81920    // i8 enc gates B: [kt4][nt32][lane64][16] (131072 B)
#define WDEC8_B  212992   // i8 dec gates B: [kt2][nt32][lane64][16] ( 65536 B)
#define SENC_B   278528   // 512 f32 per-col scales (enc)
#define SDEC_B   280576   // 512 f32 per-col scales (dec)

__device__ __forceinline__ short f2b(float f) {        // fp32 -> bf16 RNE
  union { float f; unsigned u; } c; c.f = f;
  unsigned r = c.u + 0x7fffu + ((c.u >> 16) & 1u);
  return (short)(r >> 16);
}
__device__ __forceinline__ float b2f(short s) {
  union { unsigned u; float f; } c; c.u = ((unsigned)(unsigned short)s) << 16;
  return c.f;
}
__device__ __forceinline__ float fexp2(float x) { return __builtin_amdgcn_exp2f(x); }
__device__ __forceinline__ float frcp (float x) { return __builtin_amdgcn_rcpf(x); }
__device__ __forceinline__ float tanh_acc(float x) {   // 1 - 2/(1+e^{2x})
  float e = fexp2(x * 2.885390081777927f);
  return 1.f - 2.f * frcp(1.f + e);
}
__device__ __forceinline__ float sigm(float x) {
  return frcp(1.f + fexp2(-LOG2E * x));
}
__device__ __forceinline__ float wsum64(float v) {
#pragma unroll
  for (int o = 32; o > 0; o >>= 1) v += __shfl_xor(v, o, 64);
  return v;
}
__device__ __forceinline__ float wmax64(float v) {
#pragma unroll
  for (int o = 32; o > 0; o >>= 1) v = fmaxf(v, __shfl_xor(v, o, 64));
  return v;
}

// ---- merged prep: blocks 0-159 bf16 frags, blocks 160-415 i8 quant ----
__global__ void prep_all(const float* __restrict__ We_w,
                         const float* __restrict__ Wd_w,
                         const float* __restrict__ enc_Wih,
                         const float* __restrict__ enc_Whh,
                         const float* __restrict__ dec_Whh,
                         char* __restrict__ ws8) {
  if (blockIdx.x < 160) {                // bf16 B-frags, 1 element/thread
    int e = blockIdx.x * 256 + threadIdx.x;
    if (e >= 40960) return;
    short* f16 = (short*)ws8;
    int region = e >> 14;                // 0=WHS 1=WDDC 2=WDENC
    int er = e & 16383;
    int fi = er >> 9, li = (er >> 3) & 63, jq = er & 7;
    int kt = fi >> 2, nt = fi & 3;
    int k = kt * 32 + ((li >> 4) << 3) + jq, n = nt * 16 + (li & 15);
    float v;
    if (region == 0)      v = We_w[n * 257 + k];
    else if (region == 1) v = (k < 128) ? Wd_w[n * 384 + 128 + k]
                                        : Wd_w[n * 384 + 256 + (k - 128)];
    else                  v = Wd_w[n * 384 + k];
    f16[e] = f2b(v);
    return;
  }
  int gw = ((blockIdx.x - 160) * 256 + threadIdx.x) >> 6;
  int lane = threadIdx.x & 63;
  if (gw < 512) {                        // encoder col, K=256
    int n = gw;
    float v[4]; float m = 0.f;
#pragma unroll
    for (int q = 0; q < 4; ++q) {
      int k = lane * 4 + q;
      v[q] = (k < 128) ? enc_Wih[n * 128 + k] : enc_Whh[n * 128 + (k - 128)];
      m = fmaxf(m, fabsf(v[q]));
    }
    m = wmax64(m);
    if (lane == 0) ((float*)(ws8 + SENC_B))[n] = m * C127;
    float inv = m > 0.f ? 127.f / m : 0.f;
    char* dst = ws8 + WENC8_B;
#pragma unroll
    for (int q = 0; q < 4; ++q) {
      int k = lane * 4 + q;
      int kt = k >> 6, grp = (k >> 4) & 3, b = k & 15, l16 = (n & 15) | (grp << 4);
      dst[((kt * 32 + (n >> 4)) * 64 + l16) * 16 + b] = (char)(int)rintf(v[q] * inv);
    }
  } else if (gw < 1024) {                // decoder col, K=128
    int n = gw - 512;
    float v[2]; float m = 0.f;
#pragma unroll
    for (int q = 0; q < 2; ++q) {
      int k = lane * 2 + q;
      v[q] = dec_Whh[n * 128 + k];
      m = fmaxf(m, fabsf(v[q]));
    }
    m = wmax64(m);
    if (lane == 0) ((float*)(ws8 + SDEC_B))[n] = m * C127;
    float inv = m > 0.f ? 127.f / m : 0.f;
    char* dst = ws8 + WDEC8_B;
#pragma unroll
    for (int q = 0; q < 2; ++q) {
      int k = lane * 2 + q;
      int kt = k >> 6, grp = (k >> 4) & 3, b = k & 15, l16 = (n & 15) | (grp << 4);
      dst[((kt * 32 + (n >> 4)) * 64 + l16) * 16 + b] = (char)(int)rintf(v[q] * inv);
    }
  }
}

__global__ __launch_bounds__(512, 2)
void da_rnn(const float* __restrict__ X, const float* __restrict__ y_hist,
            const float* __restrict__ We_w, const float* __restrict__ We_b,
            const float* __restrict__ ve_w,
            const float* __restrict__ enc_bih, const float* __restrict__ enc_bhh,
            const float* __restrict__ dec_Wih,
            const float* __restrict__ dec_bih, const float* __restrict__ dec_bhh,
            const float* __restrict__ Wd_b, const float* __restrict__ vd_w,
            const float* __restrict__ fc_w, const float* __restrict__ fc_b,
            const char* __restrict__ ws8, float* __restrict__ out) {
  const short* f16  = (const short*)ws8;
  const i32x4* enc8 = (const i32x4*)(ws8 + WENC8_B);
  const i32x4* dec8 = (const i32x4*)(ws8 + WDEC8_B);
  const float* senc = (const float*)(ws8 + SENC_B);
  const float* sdec = (const float*)(ws8 + SDEC_B);

  // s_A8 row 272B = 68w (4 mod 32 -> 2-way, free); s_Ahc 264sh = 132w (4 mod 32)
  __shared__ __align__(16) char  s_A8[16][272];   // gates A i8 [x_tilde ; h]
  __shared__ __align__(16) short s_Ahc[16][264];  // base/dc/proj A bf16 [h ; c]
  __shared__ short s_projT[4][64][65];            // enc_proj^T bf16
  __shared__ short s_encht[4][128][66];           // enc_hiddens [r][j][t] bf16
  __shared__ float s_gates[4][512];               // decoder only
  __shared__ float s_base[4][64];                 // enc: base ; dec: dc
  __shared__ float s_beta[4][64];
  __shared__ float s_xr[4];
  __shared__ __align__(16) float s_fn[4][8];      // attention node values
  __shared__ float2 s_wv[64];                     // (w_feat[k], ve_w[k])
  __shared__ float s_web[64], s_vd[64], s_wdb[64];
  __shared__ float s_se[512], s_sd[512];
  __shared__ float s_encb[512], s_decb[512], s_dwih[512];

  const int tid  = threadIdx.x;
  const int lane = tid & 63;
  const int w    = tid >> 6;        // wave 0..7 ; waves 0-3 own rows 0-3
  const int b0   = blockIdx.x * BB;

  // ---- init ----
  if (tid < 64) {
    s_wv[tid]  = make_float2(We_w[tid * 257 + 256], ve_w[tid]);
    s_web[tid] = We_b[tid];
    s_vd[tid]  = vd_w[tid];
    s_wdb[tid] = Wd_b[tid];
  }
  s_se[tid]   = senc[tid];
  s_sd[tid]   = sdec[tid];
  s_encb[tid] = enc_bih[tid] + enc_bhh[tid];
  s_decb[tid] = dec_bih[tid] + dec_bhh[tid];
  s_dwih[tid] = dec_Wih[tid];
  for (int i = tid; i < (16 * 272) / 4; i += 512) ((int*)s_A8)[i] = 0;
  for (int i = tid; i < (16 * 264) / 2; i += 512) ((int*)s_Ahc)[i] = 0;
  if (tid < 256) s_base[tid >> 6][tid & 63] = We_b[tid & 63];  // base_0 (h0=c0=0)
  // fc weights -> registers (used by waves 0-3 in decoder)
  const float fcw0 = fc_w[lane],       fcw1 = fc_w[64 + lane];
  const float fcw2 = fc_w[128 + lane], fcw3 = fc_w[192 + lane];
  const float fcwy = fc_w[256 + lane];
  const float fb0  = fc_b[0];

  // ---- register-resident weights ----
  i32x4 wg[4][4];                       // enc gates i8, nt = w + 8i (i = gate)
#pragma unroll
  for (int kt = 0; kt < 4; ++kt)
#pragma unroll
    for (int i = 0; i < 4; ++i)
      wg[kt][i] = enc8[(kt * 32 + (w + 8 * i)) * 64 + lane];
  bf16x8 wb[8], wp[4];
  if (w < 4) {
#pragma unroll
    for (int kt = 0; kt < 8; ++kt)
      wb[kt] = *(const bf16x8*)(f16 + WHS_E + ((kt * 4 + w) * 64 + lane) * 8);
  } else {
#pragma unroll
    for (int kt = 0; kt < 4; ++kt)
      wp[kt] = *(const bf16x8*)(f16 + WDENC_E + ((kt * 4 + (w - 4)) * 64 + lane) * 8);
  }

  // encoder LSTM state: c in regs of lanes<16 (feature w*16+lane, rows 0-3);
  // h carried one phase in regs (eh) then written at next phase top.
  float ec[4] = {0.f, 0.f, 0.f, 0.f};
  float eh[4] = {0.f, 0.f, 0.f, 0.f};

  // attention state (waves 0-3): 2 features/lane
  float x0 = 0.f, x1 = 0.f, xi = 0.f;
  const float* Xr = X + (size_t)(b0 + (w & 3)) * T_ * D_;
  if (w < 4) {
    x0 = Xr[lane]; x1 = Xr[64 + lane];
    xi = 6.f * cosf((2 * (lane >> 3) + 1) * 0.19634954084936207f);  // node
  }
  __syncthreads();

  // ====================== encoder (3 barriers/step) ======================
  for (int t = 0; t < T_; ++t) {
    // ---- P_A: input attention, in-wave, waves 0-3 (row = w) ----
    if (w < 4) {
      float x0n = 0.f, x1n = 0.f;
      if (t < T_ - 1) { x0n = Xr[(t + 1) * D_ + lane]; x1n = Xr[(t + 1) * D_ + 64 + lane]; }
      const int kc = lane & 7;           // node ni = lane>>3, 8 k-terms each
      float p = 0.f;
      const float4* wvp = (const float4*)&s_wv[kc * 8];
      const float4* bp  = (const float4*)&s_base[w][kc * 8];
      float4 bA = bp[0], bB = bp[1];
#pragma unroll
      for (int q = 0; q < 4; ++q) {
        float4 wv = wvp[q];
        float bb0 = (q < 2) ? ((q & 1) ? bA.z : bA.x) : ((q & 1) ? bB.z : bB.x);
        float bb1 = (q < 2) ? ((q & 1) ? bA.w : bA.y) : ((q & 1) ? bB.w : bB.y);
        p += wv.y * tanh_acc(fmaf(xi, wv.x, bb0));
        p += wv.w * tanh_acc(fmaf(xi, wv.z, bb1));
      }
      p += __shfl_xor(p, 1, 64); p += __shfl_xor(p, 2, 64); p += __shfl_xor(p, 4, 64);
      if (kc == 0) s_fn[w][lane >> 3] = p;          // LDS bounce (same wave)
      float4 fA = *(const float4*)&s_fn[w][0];
      float4 fB = *(const float4*)&s_fn[w][4];
      float sc0, sc1;
      {
        const float xb[8] = { 5.884711682f, 4.988817674f, 3.333421398f, 1.170541932f,
                             -1.170541932f, -3.333421398f, -4.988817674f, -5.884711682f};
        const float wbar[8] = { 0.1950903220f, -0.5555702330f, 0.8314696123f, -0.9807852804f,
                                0.9807852804f, -0.8314696123f, 0.5555702330f, -0.1950903220f};
        float fv[8] = {fA.x, fA.y, fA.z, fA.w, fB.x, fB.y, fB.z, fB.w};
        float u0 = fminf(fmaxf(x0, -6.f), 6.f), u1 = fminf(fmaxf(x1, -6.f), 6.f);
        float n0 = 0.f, d0 = 0.f, n1 = 0.f, d1 = 0.f;
#pragma unroll
        for (int i = 0; i < 8; ++i) {
          float dd0 = u0 - xb[i]; dd0 = copysignf(fmaxf(fabsf(dd0), 1e-5f), dd0);
          float dd1 = u1 - xb[i]; dd1 = copysignf(fmaxf(fabsf(dd1), 1e-5f), dd1);
          float t0 = wbar[i] * frcp(dd0), t1 = wbar[i] * frcp(dd1);
          n0 = fmaf(t0, fv[i], n0); d0 += t0;
          n1 = fmaf(t1, fv[i], n1); d1 += t1;
        }
        sc0 = n0 * frcp(d0); sc1 = n1 * frcp(d1);
      }
      float e0 = fexp2(sc0 * LOG2E), e1 = fexp2(sc1 * LOG2E);  // |sc|<=sum|ve|~2.6
      // quantize path depends only on the max-chain; sum-chain runs parallel
      float mx  = wmax64(fmaxf(e0 * fabsf(x0), e1 * fabsf(x1)));
      float inv = mx > 0.f ? 127.f * frcp(mx) : 0.f;
      s_A8[w][lane]      = (char)(int)rintf(x0 * e0 * inv);
      s_A8[w][64 + lane] = (char)(int)rintf(x1 * e1 * inv);
      float sum = wsum64(e0 + e1);
      if (lane == 0) s_xr[w] = mx * frcp(127.f * sum);
      x0 = x0n; x1 = x1n;
    }
    __syncthreads();                                            // B1
    // ---- P_GE: gates i8 GEMM + fused LSTM epilogue (all 8 waves) ----
    {
      i32x4 a0 = *(const i32x4*)&s_A8[lane & 15][  0 + ((lane >> 4) << 4)];
      i32x4 a1 = *(const i32x4*)&s_A8[lane & 15][ 64 + ((lane >> 4) << 4)];
      i32x4 a2 = *(const i32x4*)&s_A8[lane & 15][128 + ((lane >> 4) << 4)];
      i32x4 a3 = *(const i32x4*)&s_A8[lane & 15][192 + ((lane >> 4) << 4)];
      i32x4 ax[4], ah[4];
#pragma unroll
      for (int i = 0; i < 4; ++i) {
        i32x4 z = {0, 0, 0, 0};
        ax[i] = MFMAI8(a1, wg[1][i], MFMAI8(a0, wg[0][i], z));
        ah[i] = MFMAI8(a3, wg[3][i], MFMAI8(a2, wg[2][i], z));
      }
      if (lane < 16) {
        // wave w, lane<16: features col=w*16+lane, rows = reg index (C layout)
        const int col = w * 16 + lane;
        float se0 = s_se[col], se1 = s_se[col + 128];
        float se2 = s_se[col + 256], se3 = s_se[col + 384];
        float eb0 = s_encb[col], eb1 = s_encb[col + 128];
        float eb2 = s_encb[col + 256], eb3 = s_encb[col + 384];
        float sxr[4] = {s_xr[0], s_xr[1], s_xr[2], s_xr[3]};
#pragma unroll
        for (int r = 0; r < 4; ++r) {
          float gi = fmaf(se0, fmaf(sxr[r], (float)ax[0][r], C127 * (float)ah[0][r]), eb0);
          float gf = fmaf(se1, fmaf(sxr[r], (float)ax[1][r], C127 * (float)ah[1][r]), eb1);
          float gg = fmaf(se2, fmaf(sxr[r], (float)ax[2][r], C127 * (float)ah[2][r]), eb2);
          float go = fmaf(se3, fmaf(sxr[r], (float)ax[3][r], C127 * (float)ah[3][r]), eb3);
          ec[r] = sigm(gf) * ec[r] + sigm(gi) * tanh_acc(gg);
          eh[r] = sigm(go) * tanh_acc(ec[r]);
          s_Ahc[r][col]       = f2b(eh[r]);   // base/proj A (read after B2)
          s_Ahc[r][128 + col] = f2b(ec[r]);
          // s_A8 h-half + encht deferred to P_B top (WAR vs other waves' a2/a3)
        }
      }
    }
    __syncthreads();                                            // B2
    // ---- P_B: deferred h writes; base_{t+1} (w 0-3) | proj_t (w 4-7) ----
    if (lane < 16) {
      const int col = w * 16 + lane;
#pragma unroll
      for (int r = 0; r < 4; ++r) {
        s_A8[r][128 + col]  = (char)(int)rintf(eh[r] * 127.f);  // gates A, t+1
        s_encht[r][col][t]  = f2b(eh[r]);
      }
    }
    if (w < 4) {
      f32x4 acc = {0.f, 0.f, 0.f, 0.f};
#pragma unroll
      for (int kt = 0; kt < 8; ++kt) {
        bf16x8 a = *(const bf16x8*)&s_Ahc[lane & 15][kt * 32 + ((lane >> 4) << 3)];
        acc = MFMA16(a, wb[kt], acc);
      }
      if (lane < 16) {
        int col = w * 16 + lane; float bias = s_web[col];
#pragma unroll
        for (int r = 0; r < 4; ++r) s_base[r][col] = acc[r] + bias;
      }
    } else {
      f32x4 acc = {0.f, 0.f, 0.f, 0.f};
#pragma unroll
      for (int kt = 0; kt < 4; ++kt) {
        bf16x8 a = *(const bf16x8*)&s_Ahc[lane & 15][kt * 32 + ((lane >> 4) << 3)];
        acc = MFMA16(a, wp[kt], acc);
      }
      if (lane < 16) {
        int katt = (w - 4) * 16 + lane;
#pragma unroll
        for (int r = 0; r < 4; ++r) s_projT[r][katt][t] = f2b(acc[r]);
      }
    }
    __syncthreads();                                            // B3
  }

  // ====================== decoder (R6 structure, 2 barriers/step) ==========
  if (tid < 512) {
    int r = tid >> 7, j = tid & 127;
    s_Ahc[r][j] = 0; s_Ahc[r][128 + j] = 0; s_A8[r][j] = 0;
  }
  i32x4 wdg[2][8];                      // dec gates i8 (waves 4-7), nt=(w-4)*8+i
  bf16x8 wdc[8];                        // dc bf16 (waves 0-3)
  float yp = 0.f, yhd = 0.f;
  if (w >= 4) {
#pragma unroll
    for (int kt = 0; kt < 2; ++kt)
#pragma unroll
      for (int i = 0; i < 8; ++i)
        wdg[kt][i] = dec8[(kt * 32 + ((w - 4) * 8 + i)) * 64 + lane];
  } else {
#pragma unroll
    for (int kt = 0; kt < 8; ++kt)
      wdc[kt] = *(const bf16x8*)(f16 + WDDC_E + ((kt * 4 + w) * 64 + lane) * 8);
    yp = y_hist[(b0 + w) * T_ + (T_ - 1)];
    float pp = fcwy * y_hist[(b0 + w) * T_ + lane];
    yhd = wsum64(pp) + fb0;
  }
  float dd0 = 0.f, dc0 = 0.f, dd1 = 0.f, dc1 = 0.f;   // d, cc (2 feats/lane)
  __syncthreads();

  for (int hs = 0; hs < HOR_; ++hs) {
    // ---- P_dG: dec gates i8 (waves 4-7) | dc bf16 (waves 0-3) ----
    if (w >= 4) {
      i32x4 a0 = *(const i32x4*)&s_A8[lane & 15][ 0 + ((lane >> 4) << 4)];
      i32x4 a1 = *(const i32x4*)&s_A8[lane & 15][64 + ((lane >> 4) << 4)];
#pragma unroll
      for (int i = 0; i < 8; ++i) {
        i32x4 z = {0, 0, 0, 0};
        i32x4 ac = MFMAI8(a1, wdg[1][i], MFMAI8(a0, wdg[0][i], z));
        if (lane < 16) {
          int col = ((w - 4) * 8 + i) * 16 + lane;
          float sd = s_sd[col] * C127;
#pragma unroll
          for (int r = 0; r < 4; ++r) s_gates[r][col] = sd * (float)ac[r];
        }
      }
    } else {
      f32x4 acc = {0.f, 0.f, 0.f, 0.f};
#pragma unroll
      for (int kt = 0; kt < 8; ++kt) {
        bf16x8 a = *(const bf16x8*)&s_Ahc[lane & 15][kt * 32 + ((lane >> 4) << 3)];
        acc = MFMA16(a, wdc[kt], acc);
      }
      if (lane < 16) {
        int col = w * 16 + lane; float bias = s_wdb[col];
#pragma unroll
        for (int r = 0; r < 4; ++r) s_base[r][col] = acc[r] + bias;
      }
    }
    __syncthreads();                                            // Bd1
    // ---- P_dA: attention + context + epilogue + fc, in-wave (waves 0-3) ----
    if (w < 4) {
      float s = 0.f;
#pragma unroll 8
      for (int k = 0; k < 64; ++k)
        s += s_vd[k] * tanh_acc(b2f(s_projT[w][k][lane]) + s_base[w][k]);
      float e = fexp2(s * LOG2E);
      float ssum = wsum64(e);
      s_beta[w][lane] = e * frcp(ssum);
      float cx0 = 0.f, cx1 = 0.f;
      const short* e0p = &s_encht[w][lane][0];
      const short* e1p = &s_encht[w][lane + 64][0];
#pragma unroll 8
      for (int tp = 0; tp < 64; ++tp) {
        float bta = s_beta[w][tp];
        cx0 = fmaf(bta, b2f(e0p[tp]), cx0);
        cx1 = fmaf(bta, b2f(e1p[tp]), cx1);
      }
      float gi0 = s_gates[w][lane]       + s_decb[lane]       + yp * s_dwih[lane];
      float gf0 = s_gates[w][lane + 128] + s_decb[lane + 128] + yp * s_dwih[lane + 128];
      float gg0 = s_gates[w][lane + 256] + s_decb[lane + 256] + yp * s_dwih[lane + 256];
      float go0 = s_gates[w][lane + 384] + s_decb[lane + 384] + yp * s_dwih[lane + 384];
      float gi1 = s_gates[w][lane + 64]  + s_decb[lane + 64]  + yp * s_dwih[lane + 64];
      float gf1 = s_gates[w][lane + 192] + s_decb[lane + 192] + yp * s_dwih[lane + 192];
      float gg1 = s_gates[w][lane + 320] + s_decb[lane + 320] + yp * s_dwih[lane + 320];
      float go1 = s_gates[w][lane + 448] + s_decb[lane + 448] + yp * s_dwih[lane + 448];
      dc0 = sigm(gf0) * dc0 + sigm(gi0) * tanh_acc(gg0);
      dd0 = sigm(go0) * tanh_acc(dc0);
      dc1 = sigm(gf1) * dc1 + sigm(gi1) * tanh_acc(gg1);
      dd1 = sigm(go1) * tanh_acc(dc1);
      float pf = fcw0 * dd0 + fcw1 * dd1 + fcw2 * cx0 + fcw3 * cx1;
      pf = wsum64(pf);
      float o = pf + yhd;
      if (lane == 0) out[(b0 + w) * HOR_ + hs] = o;
      yp = o;
      s_Ahc[w][lane]       = f2b(dd0);
      s_Ahc[w][lane + 64]  = f2b(dd1);
      s_Ahc[w][lane + 128] = f2b(dc0);
      s_Ahc[w][lane + 192] = f2b(dc1);
      s_A8[w][lane]      = (char)(int)rintf(dd0 * 127.f);
      s_A8[w][lane + 64] = (char)(int)rintf(dd1 * 127.f);
    }
    __syncthreads();                                            // Bd2
  }
}

extern "C" void kernel_launch(void* const* d_in, const int* in_sizes, int n_in,
                              void* d_out, int out_size, void* d_ws, size_t ws_size,
                              hipStream_t stream) {
  (void)in_sizes; (void)n_in; (void)out_size; (void)ws_size;
  const float* X       = (const float*)d_in[0];
  const float* y_hist  = (const float*)d_in[1];
  const float* We_w    = (const float*)d_in[2];
  const float* We_b    = (const float*)d_in[3];
  const float* ve_w    = (const float*)d_in[4];
  // d_in[5] = ve_b : softmax-invariant, unused
  const float* enc_Wih = (const float*)d_in[6];
  const float* enc_Whh = (const float*)d_in[7];
  const float* enc_bih = (const float*)d_in[8];
  const float* enc_bhh = (const float*)d_in[9];
  const float* dec_Wih = (const float*)d_in[10];
  const float* dec_Whh = (const float*)d_in[11];
  const float* dec_bih = (const float*)d_in[12];
  const float* dec_bhh = (const float*)d_in[13];
  const float* Wd_w    = (const float*)d_in[14];
  const float* Wd_b    = (const float*)d_in[15];
  const float* vd_w    = (const float*)d_in[16];
  // d_in[17] = vd_b : softmax-invariant, unused
  const float* fc_w    = (const float*)d_in[18];
  const float* fc_b    = (const float*)d_in[19];

  char* ws8  = (char*)d_ws;
  float* out = (float*)d_out;

  prep_all<<<416, 256, 0, stream>>>(We_w, Wd_w, enc_Wih, enc_Whh, dec_Whh, ws8);
  da_rnn <<<B_ / BB, 512, 0, stream>>>(X, y_hist, We_w, We_b, ve_w,
                                       enc_bih, enc_bhh, dec_Wih, dec_bih, dec_bhh,
                                       Wd_b, vd_w, fc_w, fc_b, ws8, out);
}